// Round 5
// baseline (243.626 us; speedup 1.0000x reference)
//
#include <hip/hip_runtime.h>
#include <hip/hip_bf16.h>

#define NPTS    100000
#define KCENT   1024
#define NSEG    391          // ceil(NPTS/256)
#define NWORDS  1564         // NSEG*4 words of 64 points
#define WSTRIDE 1600         // mask words per centroid (padded)
#define MB_BLKS (NSEG*32)    // 12512 maskbuild blocks

typedef __attribute__((ext_vector_type(8))) short bf16x8;   // 8 bf16 (4 VGPRs)
typedef __attribute__((ext_vector_type(4))) float f32x4;
typedef unsigned long long u64;

__device__ __forceinline__ unsigned short f2bf(float x) {
  union { float f; unsigned u; } v; v.f = x;
  unsigned r = v.u + 0x7FFFu + ((v.u >> 16) & 1u);   // RNE
  return (unsigned short)(r >> 16);
}
__device__ __forceinline__ unsigned pk2bf(float a, float b) {
  union { __hip_bfloat162 h; unsigned u; } cv;
  cv.h = __float22bfloat162_rn(make_float2(a, b));
  return cv.u;
}
__device__ __forceinline__ bf16x8 pack_bf8(f32x4 a, f32x4 b) {
  union { bf16x8 v; unsigned u[4]; } r;
  r.u[0] = pk2bf(a[0], a[1]); r.u[1] = pk2bf(a[2], a[3]);
  r.u[2] = pk2bf(b[0], b[1]); r.u[3] = pk2bf(b[2], b[3]);
  return r.v;
}

// ---------------------------------------------------------------- maskbuild + prep (fused, independent halves)
// blocks [0, MB_BLKS): ball mask via ballot, 32 centroids x 256 points/block.
// blocks [MB_BLKS, ...): prep — featsBF bf16, coords4, W1T(stride 104,
//   augmented: k<64 feat rows, 64..66 rel rows, 67 b1), W2T/W3T(72),
//   cent gather -> d_out.
__global__ __launch_bounds__(256) void build_prep_kernel(
    const float* __restrict__ coords, const float* __restrict__ features,
    const int* __restrict__ cidx, const float* __restrict__ W1,
    const float* __restrict__ b1, const float* __restrict__ W2,
    const float* __restrict__ W3, u64* __restrict__ maskbuf,
    unsigned short* __restrict__ featsBF, f32x4* __restrict__ coords4,
    unsigned short* __restrict__ W1T, unsigned short* __restrict__ W2T,
    unsigned short* __restrict__ W3T, float* __restrict__ outCent) {
  const int bid = blockIdx.x;
  const int tid = threadIdx.x;
  if (bid < MB_BLKS) {
    const int grp = bid / NSEG, seg = bid - grp*NSEG;
    __shared__ float sC[96];
    __shared__ float sCC[32];
    if (tid < 96) sC[tid] = coords[cidx[grp*32 + tid/3]*3 + tid%3];
    __syncthreads();
    if (tid < 32) {
      float x = sC[tid*3], y = sC[tid*3+1], z = sC[tid*3+2];
      sCC[tid] = __fadd_rn(__fadd_rn(__fmul_rn(x,x), __fmul_rn(y,y)), __fmul_rn(z,z));
    }
    const int p = seg*256 + tid;
    const bool inr = p < NPTS;
    float px = 0.f, py = 0.f, pz = 0.f;
    if (inr) { px = coords[p*3]; py = coords[p*3+1]; pz = coords[p*3+2]; }
    const float pp = __fadd_rn(__fadd_rn(__fmul_rn(px,px), __fmul_rn(py,py)), __fmul_rn(pz,pz));
    __syncthreads();
    const int lane = tid & 63, wid = tid >> 6;
    u64 myw = 0ull;
    #pragma unroll
    for (int ci = 0; ci < 32; ++ci) {
      float cx = sC[ci*3], cy = sC[ci*3+1], cz = sC[ci*3+2];
      float dt = __fadd_rn(__fadd_rn(__fmul_rn(cx,px), __fmul_rn(cy,py)), __fmul_rn(cz,pz));
      float d2 = __fsub_rn(__fadd_rn(sCC[ci], pp), __fmul_rn(2.0f, dt));
      bool sel = inr && (d2 <= 0.04f);
      u64 m = __ballot(sel);
      if (lane == ci) myw = m;
    }
    if (lane < 32)
      maskbuf[(u64)(grp*32 + lane)*WSTRIDE + seg*4 + wid] = myw;
    return;
  }
  int i = (bid - MB_BLKS) * 256 + tid;
  if (i < 800000) {                       // 8 feature floats -> bf16x8
    const f32x4* src = (const f32x4*)features + i*2;
    f32x4 f0 = src[0], f1 = src[1];
    union { bf16x8 v; uint4 u; } pk; pk.v = pack_bf8(f0, f1);
    ((uint4*)featsBF)[i] = pk.u;
    return;
  }
  i -= 800000;
  if (i < NPTS) {
    coords4[i] = (f32x4){coords[3*i], coords[3*i+1], coords[3*i+2], 0.f};
    return;
  }
  i -= NPTS;
  if (i < 6144) {                         // W1T augmented, LDS-friendly stride 104
    int n = i / 96, kk = i - n*96;
    float v = 0.f;
    if (kk < 64)       v = W1[(3+kk)*64 + n];
    else if (kk < 67)  v = W1[(kk-64)*64 + n];
    else if (kk == 67) v = b1[n];
    W1T[n*104 + kk] = f2bf(v);
    return;
  }
  i -= 6144;
  if (i < 4608) { int n = i / 72, kk = i - n*72;
    W2T[n*72 + kk] = f2bf(kk < 64 ? W2[kk*64 + n] : 0.f); return; }
  i -= 4608;
  if (i < 9216) { int n = i / 72, kk = i - n*72;
    W3T[n*72 + kk] = f2bf(kk < 64 ? W3[kk*128 + n] : 0.f); return; }
  i -= 9216;
  if (i < KCENT) {
    int ci = cidx[i];
    outCent[i*3+0] = coords[ci*3+0];
    outCent[i*3+1] = coords[ci*3+1];
    outCent[i*3+2] = coords[ci*3+2];
  }
}

// ---------------------------------------------------------------- mask emit
// One 256-thread block per centroid. All 1564 words loaded coalesced up
// front; 7 rounds of block-scan over word popcounts (early exit when 1024
// reached); every thread emits its word's bits independently at its prefix
// position. Order-correct by construction, fully parallel.
__global__ __launch_bounds__(256) void maskemit_kernel(
    const u64* __restrict__ maskbuf, int* __restrict__ idxbuf,
    int* __restrict__ counts) {
  __shared__ int sTot[4];
  const int c = blockIdx.x;
  const int tid = threadIdx.x;
  const int lane = tid & 63, w = tid >> 6;
  const u64* M = maskbuf + (u64)c * WSTRIDE;
  int* out = idxbuf + (c << 10);
  u64 wv[7];
  #pragma unroll
  for (int r = 0; r < 7; ++r) {
    int widx = r*256 + tid;
    wv[r] = (widx < NWORDS) ? M[widx] : 0ull;
  }
  int base = 0;
  #pragma unroll 1
  for (int r = 0; r < 7; ++r) {
    u64 word = wv[r];
    int pc = __popcll(word);
    int inc = pc;                      // wave-inclusive scan
    #pragma unroll
    for (int d = 1; d < 64; d <<= 1) {
      int t = __shfl_up(inc, d);
      if (lane >= d) inc += t;
    }
    if (lane == 63) sTot[w] = inc;
    __syncthreads();
    int wbase = 0, tot = 0;
    #pragma unroll
    for (int i = 0; i < 4; ++i) { int v = sTot[i]; tot += v; if (i < w) wbase += v; }
    int pos = base + wbase + inc - pc;
    const int pbase = (r*256 + tid) * 64;
    while (word != 0ull && pos < KCENT) {
      int b = __ffsll(word) - 1;
      out[pos++] = pbase + b;
      word &= word - 1ull;
    }
    base += tot;
    __syncthreads();                   // sTot reuse
    if (base >= KCENT) break;          // uniform
  }
  if (tid == 0) counts[c] = base < KCENT ? base : KCENT;
}

// ---------------------------------------------------------------- fused MLP + maxpool
// 2 blocks/centroid, 4 waves, dual 16-point columns (A,B) per iteration.
// ALL weights staged in LDS (W1 stride 104, W2/W3 stride 72 — conflict-free
// b128 frag reads), shared across A/B; W3 consumed in nt-quarters to keep
// transient registers small. Register budget targets 3 waves/SIMD. Depth-2
// idx prefetch; next data loads issue right after L1 consumes current frags.
__global__ __launch_bounds__(256, 3) void fused_kernel(
    const unsigned short* __restrict__ featsBF, const f32x4* __restrict__ coords4,
    const float* __restrict__ cent, const int* __restrict__ idxbuf,
    const int* __restrict__ counts, const float* __restrict__ b2v,
    const unsigned short* __restrict__ gW1T, const unsigned short* __restrict__ gW2T,
    const unsigned short* __restrict__ gW3T, float* __restrict__ pmax) {
  __shared__ __align__(16) unsigned short sW1T[64*104];
  __shared__ __align__(16) unsigned short sW2T[64*72];
  __shared__ __align__(16) unsigned short sW3T[128*72];
  __shared__ __align__(16) unsigned short sH[4*2*16*72];  // per-wave A/B h-bufs
  __shared__ float sB2[64];
  __shared__ float sMax[512];

  const int bx = blockIdx.x;
  const int k = bx >> 1, b = bx & 1;
  const int tid = threadIdx.x;
  const int w = tid >> 6, lane = tid & 63;
  const int q = lane >> 4, cl = lane & 15;

  for (int i = tid; i < 832; i += 256)  ((uint4*)sW1T)[i] = ((const uint4*)gW1T)[i];
  for (int i = tid; i < 576; i += 256)  ((uint4*)sW2T)[i] = ((const uint4*)gW2T)[i];
  for (int i = tid; i < 1152; i += 256) ((uint4*)sW3T)[i] = ((const uint4*)gW3T)[i];
  if (tid < 64) sB2[tid] = b2v[tid];

  const int count = counts[k];
  const float cx = cent[k*3], cy = cent[k*3+1], cz = cent[k*3+2];
  unsigned short* myHA = sH + w*2304;
  unsigned short* myHB = myHA + 1152;
  const int kb = k << 10;
  __syncthreads();

  f32x4 runmax[8];
  #pragma unroll
  for (int i = 0; i < 8; ++i)
    runmax[i] = (f32x4){-__builtin_inff(), -__builtin_inff(),
                        -__builtin_inff(), -__builtin_inff()};

  const int nstrips = (count + 15) >> 4;
  const int npairs  = (nstrips + 1) >> 1;
  int pp = 2*w + b;

  // ---- pipeline preload: pair pp data; pair pp+8 idx ----
  int pA = 0, pB = 0;
  { int jA = 32*pp + cl;      if (jA < count) pA = idxbuf[kb + jA];
    int jB = 32*pp + 16 + cl; if (jB < count) pB = idxbuf[kb + jB]; }
  f32x4  c4A = coords4[pA], c4B = coords4[pB];
  bf16x8 xfA0 = *(const bf16x8*)(featsBF + pA*64 + q*8);
  bf16x8 xfA1 = *(const bf16x8*)(featsBF + pA*64 + 32 + q*8);
  bf16x8 xfB0 = *(const bf16x8*)(featsBF + pB*64 + q*8);
  bf16x8 xfB1 = *(const bf16x8*)(featsBF + pB*64 + 32 + q*8);
  int pA2 = 0, pB2 = 0;
  { int jA = 32*(pp+8) + cl;      if (jA < count) pA2 = idxbuf[kb + jA];
    int jB = 32*(pp+8) + 16 + cl; if (jB < count) pB2 = idxbuf[kb + jB]; }

  const bf16x8 zero8 = (bf16x8){0,0,0,0,0,0,0,0};

  for (; pp < npairs; pp += 8) {
    // idx prefetch two iterations ahead
    int pA3 = 0, pB3 = 0;
    { int jA = 32*(pp+16) + cl;      if (jA < count) pA3 = idxbuf[kb + jA];
      int jB = 32*(pp+16) + 16 + cl; if (jB < count) pB3 = idxbuf[kb + jB]; }

    // rel/bias B-fragments (k=64..67: rx,ry,rz,1)
    union { bf16x8 v; unsigned u[4]; } rfA, rfB;
    rfA.u[0] = pk2bf(c4A[0]-cx, c4A[1]-cy); rfA.u[1] = pk2bf(c4A[2]-cz, 1.0f);
    rfA.u[2] = 0u; rfA.u[3] = 0u;
    rfB.u[0] = pk2bf(c4B[0]-cx, c4B[1]-cy); rfB.u[1] = pk2bf(c4B[2]-cz, 1.0f);
    rfB.u[2] = 0u; rfB.u[3] = 0u;
    bf16x8 x2A = (q == 0) ? rfA.v : zero8;
    bf16x8 x2B = (q == 0) ? rfB.v : zero8;

    // ---- layer 1 (K=96, rel+bias folded; W1 frags from LDS, shared A/B) ----
    {
      f32x4 accA[4], accB[4];
      #pragma unroll
      for (int nt = 0; nt < 4; ++nt) { accA[nt] = (f32x4){0.f,0.f,0.f,0.f};
                                       accB[nt] = (f32x4){0.f,0.f,0.f,0.f}; }
      #pragma unroll
      for (int nt = 0; nt < 4; ++nt) {
        const unsigned short* wrow = sW1T + (nt*16+cl)*104 + q*8;
        bf16x8 wa0 = *(const bf16x8*)(wrow);
        accA[nt] = __builtin_amdgcn_mfma_f32_16x16x32_bf16(wa0, xfA0, accA[nt], 0,0,0);
        accB[nt] = __builtin_amdgcn_mfma_f32_16x16x32_bf16(wa0, xfB0, accB[nt], 0,0,0);
        bf16x8 wa1 = *(const bf16x8*)(wrow + 32);
        accA[nt] = __builtin_amdgcn_mfma_f32_16x16x32_bf16(wa1, xfA1, accA[nt], 0,0,0);
        accB[nt] = __builtin_amdgcn_mfma_f32_16x16x32_bf16(wa1, xfB1, accB[nt], 0,0,0);
        bf16x8 wa2 = *(const bf16x8*)(wrow + 64);
        accA[nt] = __builtin_amdgcn_mfma_f32_16x16x32_bf16(wa2, x2A, accA[nt], 0,0,0);
        accB[nt] = __builtin_amdgcn_mfma_f32_16x16x32_bf16(wa2, x2B, accB[nt], 0,0,0);
      }
      #pragma unroll
      for (int nt = 0; nt < 4; ++nt) {
        const int o = nt*16 + q*4;
        uint2 pkA = { pk2bf(fmaxf(accA[nt][0],0.f), fmaxf(accA[nt][1],0.f)),
                      pk2bf(fmaxf(accA[nt][2],0.f), fmaxf(accA[nt][3],0.f)) };
        *(uint2*)(myHA + cl*72 + o) = pkA;
        uint2 pkB = { pk2bf(fmaxf(accB[nt][0],0.f), fmaxf(accB[nt][1],0.f)),
                      pk2bf(fmaxf(accB[nt][2],0.f), fmaxf(accB[nt][3],0.f)) };
        *(uint2*)(myHB + cl*72 + o) = pkB;
      }
    }

    // current xf/c4 now dead: issue next pair's data loads (latency hides
    // under L2+L3 MFMA work)
    c4A = coords4[pA2]; c4B = coords4[pB2];
    xfA0 = *(const bf16x8*)(featsBF + pA2*64 + q*8);
    xfA1 = *(const bf16x8*)(featsBF + pA2*64 + 32 + q*8);
    xfB0 = *(const bf16x8*)(featsBF + pB2*64 + q*8);
    xfB1 = *(const bf16x8*)(featsBF + pB2*64 + 32 + q*8);

    // ---- layer 2 (W2 frags from LDS, shared A/B) ----
    {
      bf16x8 hA0 = *(const bf16x8*)(myHA + cl*72 + q*8);
      bf16x8 hA1 = *(const bf16x8*)(myHA + cl*72 + 32 + q*8);
      bf16x8 hB0 = *(const bf16x8*)(myHB + cl*72 + q*8);
      bf16x8 hB1 = *(const bf16x8*)(myHB + cl*72 + 32 + q*8);
      f32x4 accA[4], accB[4];
      #pragma unroll
      for (int nt = 0; nt < 4; ++nt) { accA[nt] = (f32x4){0.f,0.f,0.f,0.f};
                                       accB[nt] = (f32x4){0.f,0.f,0.f,0.f}; }
      #pragma unroll
      for (int nt = 0; nt < 4; ++nt) {
        const unsigned short* wrow = sW2T + (nt*16+cl)*72 + q*8;
        bf16x8 wa0 = *(const bf16x8*)(wrow);
        accA[nt] = __builtin_amdgcn_mfma_f32_16x16x32_bf16(wa0, hA0, accA[nt], 0,0,0);
        accB[nt] = __builtin_amdgcn_mfma_f32_16x16x32_bf16(wa0, hB0, accB[nt], 0,0,0);
        bf16x8 wa1 = *(const bf16x8*)(wrow + 32);
        accA[nt] = __builtin_amdgcn_mfma_f32_16x16x32_bf16(wa1, hA1, accA[nt], 0,0,0);
        accB[nt] = __builtin_amdgcn_mfma_f32_16x16x32_bf16(wa1, hB1, accB[nt], 0,0,0);
      }
      #pragma unroll
      for (int nt = 0; nt < 4; ++nt) {
        const int o = nt*16 + q*4;
        f32x4 bb = *(const f32x4*)(sB2 + o);
        uint2 pkA = { pk2bf(fmaxf(accA[nt][0]+bb[0],0.f), fmaxf(accA[nt][1]+bb[1],0.f)),
                      pk2bf(fmaxf(accA[nt][2]+bb[2],0.f), fmaxf(accA[nt][3]+bb[3],0.f)) };
        *(uint2*)(myHA + cl*72 + o) = pkA;
        uint2 pkB = { pk2bf(fmaxf(accB[nt][0]+bb[0],0.f), fmaxf(accB[nt][1]+bb[1],0.f)),
                      pk2bf(fmaxf(accB[nt][2]+bb[2],0.f), fmaxf(accB[nt][3]+bb[3],0.f)) };
        *(uint2*)(myHB + cl*72 + o) = pkB;
      }
    }

    // ---- layer 3 in nt-quarters (W3 frags transient) + merged A/B maxpool ----
    {
      bf16x8 hA0 = *(const bf16x8*)(myHA + cl*72 + q*8);
      bf16x8 hA1 = *(const bf16x8*)(myHA + cl*72 + 32 + q*8);
      bf16x8 hB0 = *(const bf16x8*)(myHB + cl*72 + q*8);
      bf16x8 hB1 = *(const bf16x8*)(myHB + cl*72 + 32 + q*8);
      const float vmA = (32*pp + cl      < count) ? 0.f : -__builtin_inff();
      const float vmB = (32*pp + 16 + cl < count) ? 0.f : -__builtin_inff();
      #pragma unroll
      for (int ntq = 0; ntq < 4; ++ntq) {
        f32x4 a3A[2], a3B[2];
        #pragma unroll
        for (int j = 0; j < 2; ++j) { a3A[j] = (f32x4){0.f,0.f,0.f,0.f};
                                      a3B[j] = (f32x4){0.f,0.f,0.f,0.f}; }
        #pragma unroll
        for (int j = 0; j < 2; ++j) {
          const int nt = ntq*2 + j;
          const unsigned short* wrow = sW3T + (nt*16+cl)*72 + q*8;
          bf16x8 w30 = *(const bf16x8*)(wrow);
          a3A[j] = __builtin_amdgcn_mfma_f32_16x16x32_bf16(w30, hA0, a3A[j], 0,0,0);
          a3B[j] = __builtin_amdgcn_mfma_f32_16x16x32_bf16(w30, hB0, a3B[j], 0,0,0);
          bf16x8 w31 = *(const bf16x8*)(wrow + 32);
          a3A[j] = __builtin_amdgcn_mfma_f32_16x16x32_bf16(w31, hA1, a3A[j], 0,0,0);
          a3B[j] = __builtin_amdgcn_mfma_f32_16x16x32_bf16(w31, hB1, a3B[j], 0,0,0);
        }
        #pragma unroll
        for (int j = 0; j < 2; ++j) {
          const int nt = ntq*2 + j;
          #pragma unroll
          for (int r = 0; r < 4; ++r)
            runmax[nt][r] = fmaxf(runmax[nt][r],
                                  fmaxf(a3A[j][r] + vmA, a3B[j][r] + vmB));
        }
      }
    }

    pA2 = pA3; pB2 = pB3;
  }

  // reduce over points (cl lanes), then across waves; write partials
  #pragma unroll
  for (int nt = 0; nt < 8; ++nt) {
    #pragma unroll
    for (int r = 0; r < 4; ++r) {
      float m = runmax[nt][r];
      m = fmaxf(m, __shfl_xor(m, 1));
      m = fmaxf(m, __shfl_xor(m, 2));
      m = fmaxf(m, __shfl_xor(m, 4));
      m = fmaxf(m, __shfl_xor(m, 8));
      runmax[nt][r] = m;
    }
    if (cl == 0) *(f32x4*)(sMax + w*128 + nt*16 + q*4) = runmax[nt];
  }
  __syncthreads();
  if (tid < 128) {
    float m = fmaxf(fmaxf(sMax[tid], sMax[128+tid]),
                    fmaxf(sMax[256+tid], sMax[384+tid]));
    pmax[bx*128 + tid] = m;
  }
}

// ---------------------------------------------------------------- combine
__global__ __launch_bounds__(256) void combine_kernel(
    const float* __restrict__ pmax, const float* __restrict__ b3,
    float* __restrict__ outF) {
  int i = blockIdx.x*256 + threadIdx.x;      // 131072 = 1024*128
  int kk = i >> 7, c = i & 127;
  float m = fmaxf(pmax[(2*kk)*128 + c], pmax[(2*kk+1)*128 + c]);
  outF[i] = fmaxf(m + b3[c], 0.f);
}

// ---------------------------------------------------------------- launch
extern "C" void kernel_launch(void* const* d_in, const int* in_sizes, int n_in,
                              void* d_out, int out_size, void* d_ws, size_t ws_size,
                              hipStream_t stream) {
  const float* coords   = (const float*)d_in[0];
  const float* features = (const float*)d_in[1];
  const int*   cidx     = (const int*)d_in[2];
  const float* W1 = (const float*)d_in[3];
  const float* b1 = (const float*)d_in[4];
  const float* W2 = (const float*)d_in[5];
  const float* b2 = (const float*)d_in[6];
  const float* W3 = (const float*)d_in[7];
  const float* b3 = (const float*)d_in[8];
  float* out = (float*)d_out;           // [0:3072) cent, [3072:) new_features

  char* ws = (char*)d_ws;
  u64* maskbuf            = (u64*)(ws + 0);                      // 13,107,200
  unsigned short* featsBF = (unsigned short*)(ws + 13107200);    // 12,800,000
  f32x4* coords4          = (f32x4*)(ws + 25907200);             //  1,600,000
  int* idxbuf  = (int*)(ws + 27507200);                          //  4,194,304
  int* counts  = (int*)(ws + 31701504);                          //      4,096
  unsigned short* W1T = (unsigned short*)(ws + 31705600);        //     13,312
  unsigned short* W2T = (unsigned short*)(ws + 31718912);        //      9,216
  unsigned short* W3T = (unsigned short*)(ws + 31728128);        //     18,432
  float* pmax = (float*)(ws + 31746560);                         //  1,048,576

  build_prep_kernel<<<MB_BLKS + 3598, 256, 0, stream>>>(
      coords, features, cidx, W1, b1, W2, W3,
      maskbuf, featsBF, coords4, W1T, W2T, W3T, out);
  maskemit_kernel<<<KCENT, 256, 0, stream>>>(maskbuf, idxbuf, counts);
  fused_kernel<<<2048, 256, 0, stream>>>(featsBF, coords4, out, idxbuf, counts,
                                         b2, W1T, W2T, W3T, pmax);
  combine_kernel<<<512, 256, 0, stream>>>(pmax, b3, out + 3072);
}

// Round 6
// 219.411 us; speedup vs baseline: 1.1104x; 1.1104x over previous
//
#include <hip/hip_runtime.h>
#include <hip/hip_bf16.h>

#define NPTS    100000
#define KCENT   1024
#define NSEG    391          // ceil(NPTS/256)
#define NWORDS  1564         // NSEG*4 words of 64 points
#define WSTRIDE 1600         // mask words per centroid (padded)
#define MB_BLKS (NSEG*32)    // 12512 maskbuild blocks

typedef __attribute__((ext_vector_type(8))) short bf16x8;   // 8 bf16 (4 VGPRs)
typedef __attribute__((ext_vector_type(4))) float f32x4;
typedef unsigned long long u64;

__device__ __forceinline__ unsigned short f2bf(float x) {
  union { float f; unsigned u; } v; v.f = x;
  unsigned r = v.u + 0x7FFFu + ((v.u >> 16) & 1u);   // RNE
  return (unsigned short)(r >> 16);
}
__device__ __forceinline__ unsigned pk2bf(float a, float b) {
  union { __hip_bfloat162 h; unsigned u; } cv;
  cv.h = __float22bfloat162_rn(make_float2(a, b));
  return cv.u;
}
__device__ __forceinline__ bf16x8 pack_bf8(f32x4 a, f32x4 b) {
  union { bf16x8 v; unsigned u[4]; } r;
  r.u[0] = pk2bf(a[0], a[1]); r.u[1] = pk2bf(a[2], a[3]);
  r.u[2] = pk2bf(b[0], b[1]); r.u[3] = pk2bf(b[2], b[3]);
  return r.v;
}

// ---------------------------------------------------------------- maskbuild + prep (fused, independent halves)
// blocks [0, MB_BLKS): ball mask via ballot, 32 centroids x 256 points/block.
// blocks [MB_BLKS, ...): prep — featsBF bf16, coords4, W1T(stride 96,
//   augmented: k<64 feat rows, 64..66 rel rows, 67 b1), W2T/W3T(72),
//   cent gather -> d_out.
__global__ __launch_bounds__(256) void build_prep_kernel(
    const float* __restrict__ coords, const float* __restrict__ features,
    const int* __restrict__ cidx, const float* __restrict__ W1,
    const float* __restrict__ b1, const float* __restrict__ W2,
    const float* __restrict__ W3, u64* __restrict__ maskbuf,
    unsigned short* __restrict__ featsBF, f32x4* __restrict__ coords4,
    unsigned short* __restrict__ W1T, unsigned short* __restrict__ W2T,
    unsigned short* __restrict__ W3T, float* __restrict__ outCent) {
  const int bid = blockIdx.x;
  const int tid = threadIdx.x;
  if (bid < MB_BLKS) {
    const int grp = bid / NSEG, seg = bid - grp*NSEG;
    __shared__ float sC[96];
    __shared__ float sCC[32];
    if (tid < 96) sC[tid] = coords[cidx[grp*32 + tid/3]*3 + tid%3];
    __syncthreads();
    if (tid < 32) {
      float x = sC[tid*3], y = sC[tid*3+1], z = sC[tid*3+2];
      sCC[tid] = __fadd_rn(__fadd_rn(__fmul_rn(x,x), __fmul_rn(y,y)), __fmul_rn(z,z));
    }
    const int p = seg*256 + tid;
    const bool inr = p < NPTS;
    float px = 0.f, py = 0.f, pz = 0.f;
    if (inr) { px = coords[p*3]; py = coords[p*3+1]; pz = coords[p*3+2]; }
    const float pp = __fadd_rn(__fadd_rn(__fmul_rn(px,px), __fmul_rn(py,py)), __fmul_rn(pz,pz));
    __syncthreads();
    const int lane = tid & 63, wid = tid >> 6;
    u64 myw = 0ull;
    #pragma unroll
    for (int ci = 0; ci < 32; ++ci) {
      float cx = sC[ci*3], cy = sC[ci*3+1], cz = sC[ci*3+2];
      float dt = __fadd_rn(__fadd_rn(__fmul_rn(cx,px), __fmul_rn(cy,py)), __fmul_rn(cz,pz));
      float d2 = __fsub_rn(__fadd_rn(sCC[ci], pp), __fmul_rn(2.0f, dt));
      bool sel = inr && (d2 <= 0.04f);
      u64 m = __ballot(sel);
      if (lane == ci) myw = m;
    }
    if (lane < 32)
      maskbuf[(u64)(grp*32 + lane)*WSTRIDE + seg*4 + wid] = myw;
    return;
  }
  int i = (bid - MB_BLKS) * 256 + tid;
  if (i < 800000) {                       // 8 feature floats -> bf16x8
    const f32x4* src = (const f32x4*)features + i*2;
    f32x4 f0 = src[0], f1 = src[1];
    union { bf16x8 v; uint4 u; } pk; pk.v = pack_bf8(f0, f1);
    ((uint4*)featsBF)[i] = pk.u;
    return;
  }
  i -= 800000;
  if (i < NPTS) {
    coords4[i] = (f32x4){coords[3*i], coords[3*i+1], coords[3*i+2], 0.f};
    return;
  }
  i -= NPTS;
  if (i < 6144) {                         // W1T augmented, stride 96
    int n = i / 96, kk = i - n*96;
    float v = 0.f;
    if (kk < 64)       v = W1[(3+kk)*64 + n];
    else if (kk < 67)  v = W1[(kk-64)*64 + n];
    else if (kk == 67) v = b1[n];
    W1T[n*96 + kk] = f2bf(v);
    return;
  }
  i -= 6144;
  if (i < 4608) { int n = i / 72, kk = i - n*72;
    W2T[n*72 + kk] = f2bf(kk < 64 ? W2[kk*64 + n] : 0.f); return; }
  i -= 4608;
  if (i < 9216) { int n = i / 72, kk = i - n*72;
    W3T[n*72 + kk] = f2bf(kk < 64 ? W3[kk*128 + n] : 0.f); return; }
  i -= 9216;
  if (i < KCENT) {
    int ci = cidx[i];
    outCent[i*3+0] = coords[ci*3+0];
    outCent[i*3+1] = coords[ci*3+1];
    outCent[i*3+2] = coords[ci*3+2];
  }
}

// ---------------------------------------------------------------- mega-fused: scan + MLP + maxpool + epilogue
// One block per centroid. Phase 1: block-parallel ordered compaction of the
// first 1024 in-radius indices from the ball mask into LDS sIdx (first 768
// words preloaded to regs; saturated balls exit in <=3 rounds, 15-sigma).
// Phase 2: round-4-proven MLP core — 4 waves, dual 16-point columns A/B,
// W1(K=96, rel+b1 folded)/W3 fragments in regs, W2 from LDS, depth-1 data
// prefetch, idx reads from LDS. Phase 3: block max-pool, +b3, relu, store.
__global__ __launch_bounds__(256, 2) void fused_kernel(
    const u64* __restrict__ maskbuf, const unsigned short* __restrict__ featsBF,
    const f32x4* __restrict__ coords4, const float* __restrict__ cent,
    const float* __restrict__ b2v, const float* __restrict__ b3v,
    const unsigned short* __restrict__ gW1T, const unsigned short* __restrict__ gW2T,
    const unsigned short* __restrict__ gW3T, float* __restrict__ outF) {
  __shared__ __align__(16) unsigned short sW2T[64*72];
  __shared__ __align__(16) unsigned short sH[4*2*16*72];  // per-wave A/B h-bufs
  __shared__ int sIdx[KCENT];
  __shared__ int sTot[4];
  __shared__ float sB2[64], sB3[128];
  __shared__ float sMax[512];

  const int k = blockIdx.x;
  const int tid = threadIdx.x;
  const int w = tid >> 6, lane = tid & 63;
  const int q = lane >> 4, cl = lane & 15;

  // issue mask preloads early (cover rounds 0..2 of the scan)
  const u64* M = maskbuf + (u64)k * WSTRIDE;
  u64 wv0 = M[tid], wv1 = M[256 + tid], wv2 = M[512 + tid];

  for (int i = tid; i < 576; i += 256) ((uint4*)sW2T)[i] = ((const uint4*)gW2T)[i];
  if (tid < 64)  sB2[tid] = b2v[tid];
  if (tid < 128) sB3[tid] = b3v[tid];

  // weight fragments in regs (round-4 scheme)
  bf16x8 w1f[3][4], w3f[2][8];
  #pragma unroll
  for (int ks = 0; ks < 3; ++ks)
    #pragma unroll
    for (int nt = 0; nt < 4; ++nt)
      w1f[ks][nt] = *(const bf16x8*)(gW1T + (nt*16+cl)*96 + ks*32 + q*8);
  #pragma unroll
  for (int ks = 0; ks < 2; ++ks)
    #pragma unroll
    for (int nt = 0; nt < 8; ++nt)
      w3f[ks][nt] = *(const bf16x8*)(gW3T + (nt*16+cl)*72 + ks*32 + q*8);

  // ---- phase 1: ordered compaction into sIdx ----
  int base = 0;
  #pragma unroll 1
  for (int r = 0; r < 7; ++r) {
    const int widx = r*256 + tid;
    u64 word = (r == 0) ? wv0 : (r == 1) ? wv1 : (r == 2) ? wv2
             : ((widx < NWORDS) ? M[widx] : 0ull);
    int pc = __popcll(word);
    int inc = pc;                      // wave-inclusive scan
    #pragma unroll
    for (int d = 1; d < 64; d <<= 1) {
      int t = __shfl_up(inc, d);
      if (lane >= d) inc += t;
    }
    if (lane == 63) sTot[w] = inc;
    __syncthreads();
    int wbase = 0, tot = 0;
    #pragma unroll
    for (int i = 0; i < 4; ++i) { int v = sTot[i]; tot += v; if (i < w) wbase += v; }
    int pos = base + wbase + inc - pc;
    const int pbase = widx * 64;
    while (word != 0ull && pos < KCENT) {
      int b = __ffsll(word) - 1;
      sIdx[pos++] = pbase + b;
      word &= word - 1ull;
    }
    base += tot;
    __syncthreads();                   // sTot reuse + sIdx visibility
    if (base >= KCENT) break;          // uniform
  }
  const int count = base < KCENT ? base : KCENT;   // uniform across block

  const float cx = cent[k*3], cy = cent[k*3+1], cz = cent[k*3+2];
  unsigned short* myHA = sH + w*2304;
  unsigned short* myHB = myHA + 1152;

  f32x4 runmax[8];
  #pragma unroll
  for (int i = 0; i < 8; ++i)
    runmax[i] = (f32x4){-__builtin_inff(), -__builtin_inff(),
                        -__builtin_inff(), -__builtin_inff()};

  // ---- phase 2: MLP over pairs of 16-point columns ----
  const int nstrips = (count + 15) >> 4;
  const int npairs  = (nstrips + 1) >> 1;
  int pp = w;

  int pA = 0, pB = 0;
  { int jA = 32*pp + cl;      if (jA < count) pA = sIdx[jA];
    int jB = 32*pp + 16 + cl; if (jB < count) pB = sIdx[jB]; }
  f32x4  c4A = coords4[pA], c4B = coords4[pB];
  bf16x8 xfA0 = *(const bf16x8*)(featsBF + pA*64 + q*8);
  bf16x8 xfA1 = *(const bf16x8*)(featsBF + pA*64 + 32 + q*8);
  bf16x8 xfB0 = *(const bf16x8*)(featsBF + pB*64 + q*8);
  bf16x8 xfB1 = *(const bf16x8*)(featsBF + pB*64 + 32 + q*8);
  int pA2 = 0, pB2 = 0;
  { int jA = 32*(pp+4) + cl;      if (jA < count) pA2 = sIdx[jA];
    int jB = 32*(pp+4) + 16 + cl; if (jB < count) pB2 = sIdx[jB]; }

  const bf16x8 zero8 = (bf16x8){0,0,0,0,0,0,0,0};

  for (; pp < npairs; pp += 4) {
    // idx (LDS) two iterations ahead
    int pA3 = 0, pB3 = 0;
    { int jA = 32*(pp+8) + cl;      if (jA < count) pA3 = sIdx[jA];
      int jB = 32*(pp+8) + 16 + cl; if (jB < count) pB3 = sIdx[jB]; }

    // rel/bias B-fragments (k=64..67: rx,ry,rz,1)
    union { bf16x8 v; unsigned u[4]; } rfA, rfB;
    rfA.u[0] = pk2bf(c4A[0]-cx, c4A[1]-cy); rfA.u[1] = pk2bf(c4A[2]-cz, 1.0f);
    rfA.u[2] = 0u; rfA.u[3] = 0u;
    rfB.u[0] = pk2bf(c4B[0]-cx, c4B[1]-cy); rfB.u[1] = pk2bf(c4B[2]-cz, 1.0f);
    rfB.u[2] = 0u; rfB.u[3] = 0u;
    bf16x8 x2A = (q == 0) ? rfA.v : zero8;
    bf16x8 x2B = (q == 0) ? rfB.v : zero8;

    // ---- layer 1 (K=96, rel+bias folded; W1 frags in regs) ----
    {
      f32x4 accA[4], accB[4];
      #pragma unroll
      for (int nt = 0; nt < 4; ++nt) { accA[nt] = (f32x4){0.f,0.f,0.f,0.f};
                                       accB[nt] = (f32x4){0.f,0.f,0.f,0.f}; }
      #pragma unroll
      for (int nt = 0; nt < 4; ++nt) {
        accA[nt] = __builtin_amdgcn_mfma_f32_16x16x32_bf16(w1f[0][nt], xfA0, accA[nt], 0,0,0);
        accB[nt] = __builtin_amdgcn_mfma_f32_16x16x32_bf16(w1f[0][nt], xfB0, accB[nt], 0,0,0);
      }
      #pragma unroll
      for (int nt = 0; nt < 4; ++nt) {
        accA[nt] = __builtin_amdgcn_mfma_f32_16x16x32_bf16(w1f[1][nt], xfA1, accA[nt], 0,0,0);
        accB[nt] = __builtin_amdgcn_mfma_f32_16x16x32_bf16(w1f[1][nt], xfB1, accB[nt], 0,0,0);
      }
      #pragma unroll
      for (int nt = 0; nt < 4; ++nt) {
        accA[nt] = __builtin_amdgcn_mfma_f32_16x16x32_bf16(w1f[2][nt], x2A, accA[nt], 0,0,0);
        accB[nt] = __builtin_amdgcn_mfma_f32_16x16x32_bf16(w1f[2][nt], x2B, accB[nt], 0,0,0);
      }
      #pragma unroll
      for (int nt = 0; nt < 4; ++nt) {
        const int o = nt*16 + q*4;
        uint2 pkA = { pk2bf(fmaxf(accA[nt][0],0.f), fmaxf(accA[nt][1],0.f)),
                      pk2bf(fmaxf(accA[nt][2],0.f), fmaxf(accA[nt][3],0.f)) };
        *(uint2*)(myHA + cl*72 + o) = pkA;
        uint2 pkB = { pk2bf(fmaxf(accB[nt][0],0.f), fmaxf(accB[nt][1],0.f)),
                      pk2bf(fmaxf(accB[nt][2],0.f), fmaxf(accB[nt][3],0.f)) };
        *(uint2*)(myHB + cl*72 + o) = pkB;
      }
    }

    // current xf/c4 dead: issue next pair's data loads (latency hides under L2+L3)
    c4A = coords4[pA2]; c4B = coords4[pB2];
    xfA0 = *(const bf16x8*)(featsBF + pA2*64 + q*8);
    xfA1 = *(const bf16x8*)(featsBF + pA2*64 + 32 + q*8);
    xfB0 = *(const bf16x8*)(featsBF + pB2*64 + q*8);
    xfB1 = *(const bf16x8*)(featsBF + pB2*64 + 32 + q*8);

    // ---- layer 2 (W2 frags from LDS, shared A/B) ----
    {
      bf16x8 hA0 = *(const bf16x8*)(myHA + cl*72 + q*8);
      bf16x8 hA1 = *(const bf16x8*)(myHA + cl*72 + 32 + q*8);
      bf16x8 hB0 = *(const bf16x8*)(myHB + cl*72 + q*8);
      bf16x8 hB1 = *(const bf16x8*)(myHB + cl*72 + 32 + q*8);
      f32x4 accA[4], accB[4];
      #pragma unroll
      for (int nt = 0; nt < 4; ++nt) { accA[nt] = (f32x4){0.f,0.f,0.f,0.f};
                                       accB[nt] = (f32x4){0.f,0.f,0.f,0.f}; }
      #pragma unroll
      for (int nt = 0; nt < 4; ++nt) {
        const unsigned short* wrow = sW2T + (nt*16+cl)*72 + q*8;
        bf16x8 wa0 = *(const bf16x8*)(wrow);
        accA[nt] = __builtin_amdgcn_mfma_f32_16x16x32_bf16(wa0, hA0, accA[nt], 0,0,0);
        accB[nt] = __builtin_amdgcn_mfma_f32_16x16x32_bf16(wa0, hB0, accB[nt], 0,0,0);
        bf16x8 wa1 = *(const bf16x8*)(wrow + 32);
        accA[nt] = __builtin_amdgcn_mfma_f32_16x16x32_bf16(wa1, hA1, accA[nt], 0,0,0);
        accB[nt] = __builtin_amdgcn_mfma_f32_16x16x32_bf16(wa1, hB1, accB[nt], 0,0,0);
      }
      #pragma unroll
      for (int nt = 0; nt < 4; ++nt) {
        const int o = nt*16 + q*4;
        f32x4 bb = *(const f32x4*)(sB2 + o);
        uint2 pkA = { pk2bf(fmaxf(accA[nt][0]+bb[0],0.f), fmaxf(accA[nt][1]+bb[1],0.f)),
                      pk2bf(fmaxf(accA[nt][2]+bb[2],0.f), fmaxf(accA[nt][3]+bb[3],0.f)) };
        *(uint2*)(myHA + cl*72 + o) = pkA;
        uint2 pkB = { pk2bf(fmaxf(accB[nt][0]+bb[0],0.f), fmaxf(accB[nt][1]+bb[1],0.f)),
                      pk2bf(fmaxf(accB[nt][2]+bb[2],0.f), fmaxf(accB[nt][3]+bb[3],0.f)) };
        *(uint2*)(myHB + cl*72 + o) = pkB;
      }
    }

    // ---- layer 3 (W3 frags in regs) + merged A/B maxpool (b3 deferred) ----
    {
      bf16x8 hA0 = *(const bf16x8*)(myHA + cl*72 + q*8);
      bf16x8 hA1 = *(const bf16x8*)(myHA + cl*72 + 32 + q*8);
      bf16x8 hB0 = *(const bf16x8*)(myHB + cl*72 + q*8);
      bf16x8 hB1 = *(const bf16x8*)(myHB + cl*72 + 32 + q*8);
      const float vmA = (32*pp + cl      < count) ? 0.f : -__builtin_inff();
      const float vmB = (32*pp + 16 + cl < count) ? 0.f : -__builtin_inff();
      f32x4 a3A[8], a3B[8];
      #pragma unroll
      for (int nt = 0; nt < 8; ++nt) { a3A[nt] = (f32x4){0.f,0.f,0.f,0.f};
                                       a3B[nt] = (f32x4){0.f,0.f,0.f,0.f}; }
      #pragma unroll
      for (int nt = 0; nt < 8; ++nt) {
        a3A[nt] = __builtin_amdgcn_mfma_f32_16x16x32_bf16(w3f[0][nt], hA0, a3A[nt], 0,0,0);
        a3B[nt] = __builtin_amdgcn_mfma_f32_16x16x32_bf16(w3f[0][nt], hB0, a3B[nt], 0,0,0);
      }
      #pragma unroll
      for (int nt = 0; nt < 8; ++nt) {
        a3A[nt] = __builtin_amdgcn_mfma_f32_16x16x32_bf16(w3f[1][nt], hA1, a3A[nt], 0,0,0);
        a3B[nt] = __builtin_amdgcn_mfma_f32_16x16x32_bf16(w3f[1][nt], hB1, a3B[nt], 0,0,0);
      }
      #pragma unroll
      for (int nt = 0; nt < 8; ++nt)
        #pragma unroll
        for (int r = 0; r < 4; ++r)
          runmax[nt][r] = fmaxf(runmax[nt][r],
                                fmaxf(a3A[nt][r] + vmA, a3B[nt][r] + vmB));
    }

    pA2 = pA3; pB2 = pB3;
  }

  // ---- phase 3: reduce over points, +b3, relu, store ----
  #pragma unroll
  for (int nt = 0; nt < 8; ++nt) {
    #pragma unroll
    for (int r = 0; r < 4; ++r) {
      float m = runmax[nt][r];
      m = fmaxf(m, __shfl_xor(m, 1));
      m = fmaxf(m, __shfl_xor(m, 2));
      m = fmaxf(m, __shfl_xor(m, 4));
      m = fmaxf(m, __shfl_xor(m, 8));
      runmax[nt][r] = m;
    }
    if (cl == 0) *(f32x4*)(sMax + w*128 + nt*16 + q*4) = runmax[nt];
  }
  __syncthreads();
  if (tid < 128) {
    float m = fmaxf(fmaxf(sMax[tid], sMax[128+tid]),
                    fmaxf(sMax[256+tid], sMax[384+tid]));
    outF[k*128 + tid] = fmaxf(m + sB3[tid], 0.f);
  }
}

// ---------------------------------------------------------------- launch
extern "C" void kernel_launch(void* const* d_in, const int* in_sizes, int n_in,
                              void* d_out, int out_size, void* d_ws, size_t ws_size,
                              hipStream_t stream) {
  const float* coords   = (const float*)d_in[0];
  const float* features = (const float*)d_in[1];
  const int*   cidx     = (const int*)d_in[2];
  const float* W1 = (const float*)d_in[3];
  const float* b1 = (const float*)d_in[4];
  const float* W2 = (const float*)d_in[5];
  const float* b2 = (const float*)d_in[6];
  const float* W3 = (const float*)d_in[7];
  const float* b3 = (const float*)d_in[8];
  float* out = (float*)d_out;           // [0:3072) cent, [3072:) new_features

  char* ws = (char*)d_ws;
  u64* maskbuf            = (u64*)(ws + 0);                      // 13,107,200
  unsigned short* featsBF = (unsigned short*)(ws + 13107200);    // 12,800,000
  f32x4* coords4          = (f32x4*)(ws + 25907200);             //  1,600,000
  unsigned short* W1T = (unsigned short*)(ws + 27507200);        //     12,288
  unsigned short* W2T = (unsigned short*)(ws + 27519488);        //      9,216
  unsigned short* W3T = (unsigned short*)(ws + 27528704);        //     18,432

  build_prep_kernel<<<MB_BLKS + 3598, 256, 0, stream>>>(
      coords, features, cidx, W1, b1, W2, W3,
      maskbuf, featsBF, coords4, W1T, W2T, W3T, out);
  fused_kernel<<<KCENT, 256, 0, stream>>>(
      maskbuf, featsBF, coords4, out, b2, b3,
      W1T, W2T, W3T, out + 3072);
}